// Round 1
// baseline (724.625 us; speedup 1.0000x reference)
//
#include <hip/hip_runtime.h>
#include <cmath>

#define BB 32
#define NN 4096
#define NC 37
#define C1 36
#define KK 100
#define DD 512
#define SCORE_TH 0.1f
#define NMS_TH 0.4f
#define CAND_CAP 4096
#define NT 256

__global__ __launch_bounds__(NT) void det_kernel(
    const float* __restrict__ boxes,      // B,N,4
    const float* __restrict__ deltas,     // B,N,4*C
    const float* __restrict__ scores,     // B,N,C
    const float* __restrict__ feats,      // B,N,D
    const float* __restrict__ im_info,    // B,3
    float* __restrict__ out)              // B,C1,K,517
{
#pragma clang fp contract(off)
    __shared__ unsigned long long cand[CAND_CAP];
    __shared__ int cnt;
    __shared__ float sbox[KK][4];
    __shared__ float sarea[KK];
    __shared__ float sval[KK];
    __shared__ int   sidx[KK];
    __shared__ int   skeep[KK];

    const int bc  = blockIdx.x;
    const int b   = bc / C1;
    const int c   = bc % C1;       // output class c -> source class c+1
    const int tid = threadIdx.x;

    if (tid == 0) cnt = 0;
    __syncthreads();

    // ---- Phase A: compact candidates (score > TH), key = (score_bits<<32)|~n
    for (int n = tid; n < NN; n += NT) {
        float v = scores[(b * NN + n) * NC + (c + 1)];
        if (v > SCORE_TH) {
            int pos = atomicAdd(&cnt, 1);
            unsigned int vb = __float_as_uint(v);   // v>0.1 => positive => uint order == float order
            cand[pos] = ((unsigned long long)vb << 32) | (unsigned int)(0xFFFFFFFFu - (unsigned int)n);
        }
    }
    __syncthreads();
    const int M = cnt;

    // pad to power of two
    int P = 128;
    while (P < M) P <<= 1;
    for (int i = M + tid; i < P; i += NT) cand[i] = 0ULL;
    __syncthreads();

    // ---- Phase B: bitonic sort descending (value desc, index asc on ties)
    for (int k = 2; k <= P; k <<= 1) {
        for (int j = k >> 1; j > 0; j >>= 1) {
            for (int i = tid; i < P; i += NT) {
                int ixj = i ^ j;
                if (ixj > i) {
                    unsigned long long a  = cand[i];
                    unsigned long long bb = cand[ixj];
                    bool desc = ((i & k) == 0);
                    if (desc ? (a < bb) : (a > bb)) {
                        cand[i]   = bb;
                        cand[ixj] = a;
                    }
                }
            }
            __syncthreads();
        }
    }

    const int V = (M < KK) ? M : KK;

    // ---- Phase C: decode + clip + scale the selected boxes (exact ref op order)
    if (tid < KK) {
        int k = tid;
        if (k < V) {
            unsigned long long key = cand[k];
            float v = __uint_as_float((unsigned int)(key >> 32));
            int   n = (int)(0xFFFFFFFFu - (unsigned int)(key & 0xFFFFFFFFull));
            sval[k] = v;
            sidx[k] = n;
            skeep[k] = 1;

            const float* bp = boxes + (b * NN + n) * 4;
            float bx1 = bp[0], by1 = bp[1], bx2 = bp[2], by2 = bp[3];
            const float* dp = deltas + ((b * NN + n) * NC + (c + 1)) * 4;
            float d0 = dp[0] * 0.1f;
            float d1 = dp[1] * 0.1f;
            float d2 = dp[2] * 0.2f;
            float d3 = dp[3] * 0.2f;

            float w  = bx2 - bx1 + 1.0f;
            float h  = by2 - by1 + 1.0f;
            float cx = bx1 + 0.5f * w;
            float cy = by1 + 0.5f * h;
            float pcx = d0 * w + cx;
            float pcy = d1 * h + cy;
            float pw  = (float)exp((double)d2) * w;   // correctly-rounded f32 exp
            float ph  = (float)exp((double)d3) * h;

            float hmax = im_info[b * 3 + 0] - 1.0f;
            float wmax = im_info[b * 3 + 1] - 1.0f;
            float sc   = im_info[b * 3 + 2];

            float x1p = fminf(fmaxf(pcx - 0.5f * pw, 0.0f), wmax);
            float y1p = fminf(fmaxf(pcy - 0.5f * ph, 0.0f), hmax);
            float x2p = fminf(fmaxf(pcx + 0.5f * pw, 0.0f), wmax);
            float y2p = fminf(fmaxf(pcy + 0.5f * ph, 0.0f), hmax);
            x1p = x1p / sc; y1p = y1p / sc; x2p = x2p / sc; y2p = y2p / sc;

            sbox[k][0] = x1p; sbox[k][1] = y1p; sbox[k][2] = x2p; sbox[k][3] = y2p;
            sarea[k] = (x2p - x1p) * (y2p - y1p);
        } else {
            sval[k] = 0.0f; sidx[k] = 0; skeep[k] = 0;
            sbox[k][0] = sbox[k][1] = sbox[k][2] = sbox[k][3] = 0.0f;
            sarea[k] = 0.0f;
        }
    }
    __syncthreads();

    // ---- Phase D: greedy NMS (serial over i, parallel over j)
    for (int i = 0; i < V; ++i) {
        if (tid < KK && tid > i && skeep[i] && skeep[tid]) {
            float ax1 = sbox[i][0], ay1 = sbox[i][1], ax2 = sbox[i][2], ay2 = sbox[i][3];
            float qx1 = sbox[tid][0], qy1 = sbox[tid][1], qx2 = sbox[tid][2], qy2 = sbox[tid][3];
            float ltx = fmaxf(ax1, qx1);
            float lty = fmaxf(ay1, qy1);
            float rbx = fminf(ax2, qx2);
            float rby = fminf(ay2, qy2);
            float iw = fmaxf(rbx - ltx, 0.0f);
            float ih = fmaxf(rby - lty, 0.0f);
            float inter = iw * ih;
            float denom = sarea[i] + sarea[tid];
            denom = denom - inter;
            denom = denom + 1e-8f;
            float iou = inter / denom;
            if (iou > NMS_TH) skeep[tid] = 0;
        }
        __syncthreads();
    }

    // ---- Phase E: emit 100 rows of 517 (box,score,feats) or zeros
    const long long obase = (long long)bc * (KK * 517);
    for (int k = 0; k < KK; ++k) {
        float* orow = out + obase + (long long)k * 517;
        if (skeep[k]) {
            int n = sidx[k];
            const float* fp = feats + (long long)(b * NN + n) * DD;
            if (tid < 4)       orow[tid] = sbox[k][tid];
            else if (tid == 4) orow[4]   = sval[k];
            for (int j = tid; j < DD; j += NT) orow[5 + j] = fp[j];
        } else {
            for (int j = tid; j < 517; j += NT) orow[j] = 0.0f;
        }
    }
}

extern "C" void kernel_launch(void* const* d_in, const int* in_sizes, int n_in,
                              void* d_out, int out_size, void* d_ws, size_t ws_size,
                              hipStream_t stream) {
    const float* boxes    = (const float*)d_in[0];
    const float* deltas   = (const float*)d_in[1];
    const float* scores   = (const float*)d_in[2];
    const float* feats    = (const float*)d_in[3];
    const float* im_info  = (const float*)d_in[4];
    float* out = (float*)d_out;

    det_kernel<<<dim3(BB * C1), dim3(NT), 0, stream>>>(
        boxes, deltas, scores, feats, im_info, out);
}

// Round 2
// 615.465 us; speedup vs baseline: 1.1774x; 1.1774x over previous
//
#include <hip/hip_runtime.h>
#include <cmath>

#define BB 32
#define NN 4096
#define NC 37
#define C1 36
#define KK 100
#define DD 512
#define SCORE_TH 0.1f
#define NMS_TH 0.4f
#define CAND_CAP 4096
#define NT 256
#define NROWS (BB * C1 * KK)   // 115200

// ---------------- K1: per-(b,c) selection: threshold -> top-K -> decode -> NMS
__global__ __launch_bounds__(NT) void select_kernel(
    const float* __restrict__ boxes,      // B,N,4
    const float* __restrict__ deltas,     // B,N,4*C
    const float* __restrict__ scores,     // B,N,C
    const float* __restrict__ im_info,    // B,3
    float* __restrict__ wbox,             // NROWS*4
    float* __restrict__ wval,             // NROWS
    int*   __restrict__ widx,             // NROWS
    int*   __restrict__ wkeep)            // NROWS
{
#pragma clang fp contract(off)
    __shared__ unsigned long long cand[CAND_CAP];
    __shared__ int cnt;
    __shared__ float sbox[KK][4];
    __shared__ float sarea[KK];
    __shared__ float sval[KK];
    __shared__ int   sidx[KK];
    __shared__ int   skeep[KK];

    const int bc  = blockIdx.x;
    const int b   = bc / C1;
    const int c   = bc % C1;       // output class c -> source class c+1
    const int tid = threadIdx.x;

    if (tid == 0) cnt = 0;
    __syncthreads();

    // ---- Phase A: compact candidates (score > TH), key = (score_bits<<32)|~n
    for (int n = tid; n < NN; n += NT) {
        float v = scores[(b * NN + n) * NC + (c + 1)];
        if (v > SCORE_TH) {
            int pos = atomicAdd(&cnt, 1);
            unsigned int vb = __float_as_uint(v);   // v>0.1 => positive => uint order == float order
            cand[pos] = ((unsigned long long)vb << 32) | (unsigned int)(0xFFFFFFFFu - (unsigned int)n);
        }
    }
    __syncthreads();
    const int M = cnt;

    // pad to power of two
    int P = 128;
    while (P < M) P <<= 1;
    for (int i = M + tid; i < P; i += NT) cand[i] = 0ULL;
    __syncthreads();

    // ---- Phase B: bitonic sort descending (value desc, index asc on ties)
    for (int k = 2; k <= P; k <<= 1) {
        for (int j = k >> 1; j > 0; j >>= 1) {
            for (int i = tid; i < P; i += NT) {
                int ixj = i ^ j;
                if (ixj > i) {
                    unsigned long long a  = cand[i];
                    unsigned long long bb = cand[ixj];
                    bool desc = ((i & k) == 0);
                    if (desc ? (a < bb) : (a > bb)) {
                        cand[i]   = bb;
                        cand[ixj] = a;
                    }
                }
            }
            __syncthreads();
        }
    }

    const int V = (M < KK) ? M : KK;

    // ---- Phase C: decode + clip + scale the selected boxes (exact ref op order)
    if (tid < KK) {
        int k = tid;
        if (k < V) {
            unsigned long long key = cand[k];
            float v = __uint_as_float((unsigned int)(key >> 32));
            int   n = (int)(0xFFFFFFFFu - (unsigned int)(key & 0xFFFFFFFFull));
            sval[k] = v;
            sidx[k] = n;
            skeep[k] = 1;

            const float* bp = boxes + (b * NN + n) * 4;
            float bx1 = bp[0], by1 = bp[1], bx2 = bp[2], by2 = bp[3];
            const float* dp = deltas + ((b * NN + n) * NC + (c + 1)) * 4;
            float d0 = dp[0] * 0.1f;
            float d1 = dp[1] * 0.1f;
            float d2 = dp[2] * 0.2f;
            float d3 = dp[3] * 0.2f;

            float w  = bx2 - bx1 + 1.0f;
            float h  = by2 - by1 + 1.0f;
            float cx = bx1 + 0.5f * w;
            float cy = by1 + 0.5f * h;
            float pcx = d0 * w + cx;
            float pcy = d1 * h + cy;
            float pw  = (float)exp((double)d2) * w;   // correctly-rounded f32 exp
            float ph  = (float)exp((double)d3) * h;

            float hmax = im_info[b * 3 + 0] - 1.0f;
            float wmax = im_info[b * 3 + 1] - 1.0f;
            float sc   = im_info[b * 3 + 2];

            float x1p = fminf(fmaxf(pcx - 0.5f * pw, 0.0f), wmax);
            float y1p = fminf(fmaxf(pcy - 0.5f * ph, 0.0f), hmax);
            float x2p = fminf(fmaxf(pcx + 0.5f * pw, 0.0f), wmax);
            float y2p = fminf(fmaxf(pcy + 0.5f * ph, 0.0f), hmax);
            x1p = x1p / sc; y1p = y1p / sc; x2p = x2p / sc; y2p = y2p / sc;

            sbox[k][0] = x1p; sbox[k][1] = y1p; sbox[k][2] = x2p; sbox[k][3] = y2p;
            sarea[k] = (x2p - x1p) * (y2p - y1p);
        } else {
            sval[k] = 0.0f; sidx[k] = 0; skeep[k] = 0;
            sbox[k][0] = sbox[k][1] = sbox[k][2] = sbox[k][3] = 0.0f;
            sarea[k] = 0.0f;
        }
    }
    __syncthreads();

    // ---- Phase D: greedy NMS (serial over i, parallel over j)
    for (int i = 0; i < V; ++i) {
        if (tid < KK && tid > i && skeep[i] && skeep[tid]) {
            float ax1 = sbox[i][0], ay1 = sbox[i][1], ax2 = sbox[i][2], ay2 = sbox[i][3];
            float qx1 = sbox[tid][0], qy1 = sbox[tid][1], qx2 = sbox[tid][2], qy2 = sbox[tid][3];
            float ltx = fmaxf(ax1, qx1);
            float lty = fmaxf(ay1, qy1);
            float rbx = fminf(ax2, qx2);
            float rby = fminf(ay2, qy2);
            float iw = fmaxf(rbx - ltx, 0.0f);
            float ih = fmaxf(rby - lty, 0.0f);
            float inter = iw * ih;
            float denom = sarea[i] + sarea[tid];
            denom = denom - inter;
            denom = denom + 1e-8f;
            float iou = inter / denom;
            if (iou > NMS_TH) skeep[tid] = 0;
        }
        __syncthreads();
    }

    // ---- write per-row metadata to workspace
    if (tid < KK) {
        int r = bc * KK + tid;
        wkeep[r] = skeep[tid];
        widx[r]  = sidx[tid];
        wval[r]  = sval[tid];
        wbox[r * 4 + 0] = sbox[tid][0];
        wbox[r * 4 + 1] = sbox[tid][1];
        wbox[r * 4 + 2] = sbox[tid][2];
        wbox[r * 4 + 3] = sbox[tid][3];
    }
}

// ---------------- K2: one block per output row, fully parallel streaming emit
__global__ __launch_bounds__(128) void emit_kernel(
    const float* __restrict__ feats,      // B,N,D
    const float* __restrict__ wbox,
    const float* __restrict__ wval,
    const int*   __restrict__ widx,
    const int*   __restrict__ wkeep,
    float* __restrict__ out)
{
    const int r   = blockIdx.x;           // bc*KK + k
    const int tid = threadIdx.x;
    const long long obase = (long long)r * 517;

    if (wkeep[r]) {
        const int bc = r / KK;
        const int b  = bc / C1;
        const int n  = widx[r];
        const float* fp = feats + (long long)(b * NN + n) * DD;
        for (int j = tid; j < 517; j += 128) {
            float v;
            if (j < 4)       v = wbox[r * 4 + j];
            else if (j == 4) v = wval[r];
            else             v = fp[j - 5];
            out[obase + j] = v;
        }
    } else {
        for (int j = tid; j < 517; j += 128) out[obase + j] = 0.0f;
    }
}

extern "C" void kernel_launch(void* const* d_in, const int* in_sizes, int n_in,
                              void* d_out, int out_size, void* d_ws, size_t ws_size,
                              hipStream_t stream) {
    const float* boxes    = (const float*)d_in[0];
    const float* deltas   = (const float*)d_in[1];
    const float* scores   = (const float*)d_in[2];
    const float* feats    = (const float*)d_in[3];
    const float* im_info  = (const float*)d_in[4];
    float* out = (float*)d_out;

    // workspace layout
    char* ws = (char*)d_ws;
    float* wbox = (float*)ws;                         ws += (size_t)NROWS * 4 * sizeof(float);
    float* wval = (float*)ws;                         ws += (size_t)NROWS * sizeof(float);
    int*   widx = (int*)ws;                           ws += (size_t)NROWS * sizeof(int);
    int*   wkeep = (int*)ws;

    select_kernel<<<dim3(BB * C1), dim3(NT), 0, stream>>>(
        boxes, deltas, scores, im_info, wbox, wval, widx, wkeep);
    emit_kernel<<<dim3(NROWS), dim3(128), 0, stream>>>(
        feats, wbox, wval, widx, wkeep, out);
}